// Round 4
// baseline (156.563 us; speedup 1.0000x reference)
//
#include <hip/hip_runtime.h>
#include <math.h>

namespace {

constexpr int Hh = 112, Ww = 112, Cc = 64, Nn = 16;
constexpr int OHh = 56, OWw = 56;
constexpr int HW = Hh * Ww;            // 12544
constexpr int OP = OHh * OWw;          // 3136 positions per n
constexpr int NP = Nn * OP;            // 50176 positions total
constexpr float BN_EPS_F = 1e-5f;
constexpr float CLAMP_MIN_F = 1e-4f;
constexpr int TP = 12;                 // wave tile pitch: rows start at banks {0,4,..,28} -> 2-way free
constexpr int NSTAT = 8;               // stat copy spread (atomic contention)

__device__ __forceinline__ int reflect_idx(int t) {
    t = t < 0 ? -t : t;
    t = (t >= Hh) ? (2 * Hh - 2 - t) : t;
    return t;
}

// ---------------- K1: one WAVE per 8x8 output tile; barrier-free channel loop.
// Private double-buffered 10x12 LDS halo; lgkmcnt-only waits keep global loads
// in flight across iterations. Emits stats (8-way spread) + raw sigma at even pos.
__global__ __launch_bounds__(64) void conv_stats_sig_kernel(
    const float* __restrict__ x, const float* __restrict__ wgt,
    double* __restrict__ stats /* [NSTAT][18] */, float* __restrict__ sig_raw /* [9][NP] */)
{
    __shared__ float tile[2][10 * TP];

    const int lane = threadIdx.x;
    const int t = blockIdx.x;                 // 196 tiles: 14x14 of 8x8
    const int n = blockIdx.y;
    const int h0 = (t / 14) * 8, w0 = (t % 14) * 8;
    const int lx = lane & 7, ly = lane >> 3;

    // halo (10x10 = 100 elems): elem i0 = lane, i1 = lane + 64 (lanes < 36)
    const bool v1 = (lane < 36);
    int l0, g0, l1, g1;
    {
        const int r = lane / 10, c = lane - r * 10;
        l0 = r * TP + c;
        g0 = reflect_idx(h0 - 1 + r) * Ww + reflect_idx(w0 - 1 + c);
    }
    {
        const int i = lane + 64;
        const int r = i / 10, c = i - r * 10;   // r in [6,9]
        l1 = r * TP + c;
        g1 = reflect_idx(h0 - 1 + r) * Ww + reflect_idx(w0 - 1 + c);
    }

    const float* xb = x + (size_t)n * Cc * HW;

    // prologue: ch0 -> buf0; ch1 in regs
    float pa = xb[g0];
    float pb = v1 ? xb[g1] : 0.f;
    tile[0][l0] = pa;
    if (v1) tile[0][l1] = pb;
    pa = xb[HW + g0];
    if (v1) pb = xb[HW + g1];

    float acc[9];
#pragma unroll
    for (int k = 0; k < 9; ++k) acc[k] = 0.f;

    asm volatile("s_waitcnt lgkmcnt(0)" ::: "memory");
    __builtin_amdgcn_sched_barrier(0);

    for (int c = 0; c < Cc; ++c) {
        // write next channel's buffer (regs loaded one iteration ago)
        if (c + 1 < Cc) {
            float* tn = tile[(c + 1) & 1];
            tn[l0] = pa;
            if (v1) tn[l1] = pb;
        }
        // issue loads for channel c+2 (stay in flight across the lgkm wait)
        if (c + 2 < Cc) {
            const float* xc = xb + (size_t)(c + 2) * HW;
            pa = xc[g0];
            if (v1) pb = xc[g1];
        }
        asm volatile("s_waitcnt lgkmcnt(0)" ::: "memory");
        __builtin_amdgcn_sched_barrier(0);

        const float* tl = tile[c & 1];
        float xv[9];
#pragma unroll
        for (int dy = 0; dy < 3; ++dy)
#pragma unroll
            for (int dx = 0; dx < 3; ++dx)
                xv[dy * 3 + dx] = tl[(ly + dy) * TP + (lx + dx)];
#pragma unroll
        for (int k = 0; k < 9; ++k) {
            const float* wk = wgt + ((size_t)k * Cc + c) * 9;
#pragma unroll
            for (int q = 0; q < 9; ++q)
                acc[k] = fmaf(wk[q], xv[q], acc[k]);
        }
    }

    // raw sigma at even positions, tap-major [9][NP]
    if (((ly & 1) == 0) && ((lx & 1) == 0)) {
        const int oh = (h0 + ly) >> 1, ow = (w0 + lx) >> 1;
        const int p = n * OP + oh * OWw + ow;
#pragma unroll
        for (int k = 0; k < 9; ++k) sig_raw[(size_t)k * NP + p] = acc[k];
    }

    // wave-reduce stats, spread atomics over NSTAT copies
    double* st = stats + (size_t)(t & (NSTAT - 1)) * 18;
#pragma unroll
    for (int k = 0; k < 9; ++k) {
        float s = acc[k];
        float q = acc[k] * acc[k];
#pragma unroll
        for (int off = 32; off > 0; off >>= 1) {
            s += __shfl_down(s, off, 64);
            q += __shfl_down(q, off, 64);
        }
        if (lane == 0) {
            atomicAdd(&st[k], (double)s);
            atomicAdd(&st[9 + k], (double)q);
        }
    }
}

// ---------------- K1b: BN + clamp + tap-normalize once per position (tap-major).
__global__ __launch_bounds__(256) void normalize_kernel(
    const float* __restrict__ sig_raw, const float* __restrict__ gamma,
    const float* __restrict__ beta, const double* __restrict__ stats,
    float* __restrict__ sig_norm /* [9][NP] */)
{
    __shared__ float mean_s[9], istd_s[9], gam_s[9], bet_s[9];
    const int tid = threadIdx.x;
    if (tid < 9) {
        double s = 0.0, q = 0.0;
        for (int r = 0; r < NSTAT; ++r) { s += stats[r * 18 + tid]; q += stats[r * 18 + 9 + tid]; }
        const double cnt = (double)Nn * HW;
        const double m = s / cnt;
        const double v = q / cnt - m * m;
        mean_s[tid] = (float)m;
        istd_s[tid] = (float)(1.0 / sqrt(v + (double)BN_EPS_F));
        gam_s[tid] = gamma[tid];
        bet_s[tid] = beta[tid];
    }
    __syncthreads();

    const int p = blockIdx.x * 256 + tid;   // NP = 196 * 256 exactly
    float s[9], ssum = 0.f;
#pragma unroll
    for (int k = 0; k < 9; ++k) {
        float v = fmaf((sig_raw[(size_t)k * NP + p] - mean_s[k]) * istd_s[k], gam_s[k], bet_s[k]);
        v = fmaxf(v, CLAMP_MIN_F);
        s[k] = v;
        ssum += v;
    }
    const float inv = 1.f / ssum;
#pragma unroll
    for (int k = 0; k < 9; ++k) sig_norm[(size_t)k * NP + p] = s[k] * inv;
}

// ---------------- K2: streaming apply — thread per output, 4 chunks/block.
__global__ __launch_bounds__(256) void apply_kernel(
    const float* __restrict__ x, const float* __restrict__ sig_norm,
    float* __restrict__ out)
{
    const int tid = threadIdx.x;
    const int base = blockIdx.x * 1024;
#pragma unroll
    for (int u = 0; u < 4; ++u) {
        const int p = base + u * 256 + tid;
        const int ow = p % OWw;
        const int t1 = p / OWw;
        const int oh = t1 % OHh;
        const int nc = t1 / OHh;
        const int n = nc >> 6;

        const float* xc = x + (size_t)nc * HW;
        const int sb = n * OP + oh * OWw + ow;

        const int r0 = (oh == 0) ? 1 : (2 * oh - 1);
        const int r1 = 2 * oh, r2 = 2 * oh + 1;
        const int c0 = (ow == 0) ? 1 : (2 * ow - 1);
        const int c1 = 2 * ow, c2 = 2 * ow + 1;

        float o = 0.f;
        o = fmaf(sig_norm[0 * NP + sb], xc[r0 * Ww + c0], o);
        o = fmaf(sig_norm[1 * NP + sb], xc[r0 * Ww + c1], o);
        o = fmaf(sig_norm[2 * NP + sb], xc[r0 * Ww + c2], o);
        o = fmaf(sig_norm[3 * NP + sb], xc[r1 * Ww + c0], o);
        o = fmaf(sig_norm[4 * NP + sb], xc[r1 * Ww + c1], o);
        o = fmaf(sig_norm[5 * NP + sb], xc[r1 * Ww + c2], o);
        o = fmaf(sig_norm[6 * NP + sb], xc[r2 * Ww + c0], o);
        o = fmaf(sig_norm[7 * NP + sb], xc[r2 * Ww + c1], o);
        o = fmaf(sig_norm[8 * NP + sb], xc[r2 * Ww + c2], o);
        out[p] = o;
    }
}

} // namespace

extern "C" void kernel_launch(void* const* d_in, const int* in_sizes, int n_in,
                              void* d_out, int out_size, void* d_ws, size_t ws_size,
                              hipStream_t stream) {
    const float* x     = (const float*)d_in[0];
    const float* wgt   = (const float*)d_in[1];
    const float* gamma = (const float*)d_in[2];
    const float* beta  = (const float*)d_in[3];
    float* out = (float*)d_out;

    double* stats   = (double*)d_ws;                                   // NSTAT*18 doubles = 1152 B
    float* sig_raw  = (float*)((char*)d_ws + 2048);                    // 9*NP floats
    float* sig_norm = (float*)((char*)d_ws + 2048 + (size_t)9 * NP * 4);

    hipMemsetAsync(d_ws, 0, 2048, stream);
    conv_stats_sig_kernel<<<dim3(196, 16), 64, 0, stream>>>(x, wgt, stats, sig_raw);
    normalize_kernel<<<NP / 256, 256, 0, stream>>>(sig_raw, gamma, beta, stats, sig_norm);
    apply_kernel<<<(Nn * Cc * OP) / 1024, 256, 0, stream>>>(x, sig_norm, out);
}

// Round 5
// 148.212 us; speedup vs baseline: 1.0563x; 1.0563x over previous
//
#include <hip/hip_runtime.h>
#include <math.h>

namespace {

constexpr int Hh = 112, Ww = 112, Cc = 64, Nn = 16;
constexpr int OHh = 56, OWw = 56;
constexpr int HW = Hh * Ww;            // 12544
constexpr int OP = OHh * OWw;          // 3136
constexpr int NP = Nn * OP;            // 50176
constexpr float BN_EPS_F = 1e-5f;
constexpr float CLAMP_MIN_F = 1e-4f;
constexpr int TP = 24;                 // rows at banks {0,24,16,8}+tx -> exact 2-way (free)
constexpr int TILE_ELEMS = 18 * 18;    // 324
constexpr int NSTAT = 16;              // stats atomic spread

__device__ __forceinline__ int reflect_idx(int t) {
    t = t < 0 ? -t : t;
    t = (t >= Hh) ? (2 * Hh - 2 - t) : t;
    return t;
}

// raw barrier: ds_writes visible (lgkm drained) but global loads STAY IN FLIGHT
#define FENCE_BARRIER() asm volatile("s_waitcnt lgkmcnt(0)\ns_barrier" ::: "memory")

__device__ __forceinline__ void conv_step(const float* __restrict__ tl,
                                          const float* __restrict__ wgt,
                                          int c, int ty, int tx, float acc[9]) {
    float xv[9];
#pragma unroll
    for (int dy = 0; dy < 3; ++dy) {
        const float* row = tl + (ty + dy) * TP + tx;
#pragma unroll
        for (int dx = 0; dx < 3; ++dx) xv[dy * 3 + dx] = row[dx];
    }
#pragma unroll
    for (int k = 0; k < 9; ++k) {
        const float* wk = wgt + ((size_t)k * Cc + c) * 9;
#pragma unroll
        for (int q = 0; q < 9; ++q) acc[k] = fmaf(wk[q], xv[q], acc[k]);
    }
}

// K1: full-res conv (64ch -> 9 taps); R2 structure + raw barriers + 3-deep prefetch.
__global__ __launch_bounds__(256) void conv_stats_sig_kernel(
    const float* __restrict__ x, const float* __restrict__ wgt,
    double* __restrict__ stats /* [NSTAT][18] */, float* __restrict__ sig_raw /* [9][NP] */)
{
    __shared__ float tile[2][18 * TP];
    __shared__ float red_sum[4][9], red_sq[4][9];

    const int tid = threadIdx.x;
    const int tx = tid & 15, ty = tid >> 4;
    const int n = blockIdx.y;
    const int h0 = (int)(blockIdx.x / 7) * 16;
    const int w0 = (int)(blockIdx.x % 7) * 16;

    const int i0 = tid, i1 = tid + 256;
    const bool v1 = (i1 < TILE_ELEMS);
    int l0, g0, l1 = 0, g1 = 0;
    {
        const int r = i0 / 18, cl = i0 - r * 18;
        l0 = r * TP + cl;
        g0 = reflect_idx(h0 - 1 + r) * Ww + reflect_idx(w0 - 1 + cl);
    }
    if (v1) {
        const int r = i1 / 18, cl = i1 - r * 18;
        l1 = r * TP + cl;
        g1 = reflect_idx(h0 - 1 + r) * Ww + reflect_idx(w0 - 1 + cl);
    }

    const float* xb = x + (size_t)n * Cc * HW;

    // prologue: ch0 -> buf0; ch1 -> set1; ch2 -> set2 (sets cycle mod 4: ch k -> set k&3)
    float a0, b0 = 0.f, a1, b1 = 0.f, a2, b2 = 0.f, a3, b3 = 0.f;
    a0 = xb[g0]; if (v1) b0 = xb[g1];
    tile[0][l0] = a0; if (v1) tile[0][l1] = b0;
    a1 = xb[HW + g0];     if (v1) b1 = xb[HW + g1];
    a2 = xb[2 * HW + g0]; if (v1) b2 = xb[2 * HW + g1];
    FENCE_BARRIER();

    float acc[9];
#pragma unroll
    for (int k = 0; k < 9; ++k) acc[k] = 0.f;

    // phase(c): write buf[(c+1)&1] <- set (c+1)&3 ; issue ch c+3 -> set (c+3)&3 ;
    //           compute ch c from buf[c&1] ; fence+barrier (global loads stay in flight)
#define PHASE(c, wa, wb, la, lb, br, bw)                                         \
    {                                                                            \
        if ((c) + 1 < Cc) { float* tw = tile[bw]; tw[l0] = wa; if (v1) tw[l1] = wb; } \
        if ((c) + 3 < Cc) { const float* xc = xb + (size_t)((c) + 3) * HW;       \
                            la = xc[g0]; if (v1) lb = xc[g1]; }                  \
        conv_step(tile[br], wgt, (c), ty, tx, acc);                              \
        if ((c) < Cc - 1) FENCE_BARRIER();                                       \
    }

    for (int f = 0; f < Cc / 4; ++f) {
        const int c = 4 * f;
        PHASE(c + 0, a1, b1, a3, b3, 0, 1);
        PHASE(c + 1, a2, b2, a0, b0, 1, 0);
        PHASE(c + 2, a3, b3, a1, b1, 0, 1);
        PHASE(c + 3, a0, b0, a2, b2, 1, 0);
    }
#undef PHASE

    // raw sigma at even positions, tap-major [9][NP]
    if (((ty & 1) == 0) && ((tx & 1) == 0)) {
        const int oh = (h0 + ty) >> 1, ow = (w0 + tx) >> 1;
        const int p = n * OP + oh * OWw + ow;
#pragma unroll
        for (int k = 0; k < 9; ++k) sig_raw[(size_t)k * NP + p] = acc[k];
    }

    // stats reduction -> spread atomics
    const int lane = tid & 63;
    const int wv = tid >> 6;
#pragma unroll
    for (int k = 0; k < 9; ++k) {
        float s = acc[k];
        float q = acc[k] * acc[k];
#pragma unroll
        for (int off = 32; off > 0; off >>= 1) {
            s += __shfl_down(s, off, 64);
            q += __shfl_down(q, off, 64);
        }
        if (lane == 0) { red_sum[wv][k] = s; red_sq[wv][k] = q; }
    }
    __syncthreads();
    if (tid < 9) {
        const float s = red_sum[0][tid] + red_sum[1][tid] + red_sum[2][tid] + red_sum[3][tid];
        const float q = red_sq[0][tid] + red_sq[1][tid] + red_sq[2][tid] + red_sq[3][tid];
        double* st = stats + (size_t)((blockIdx.x + 49 * blockIdx.y) & (NSTAT - 1)) * 18;
        atomicAdd(&st[tid], (double)s);
        atomicAdd(&st[9 + tid], (double)q);
    }
}

// K1b: BN + clamp + tap-normalize once per position (tap-major in/out).
__global__ __launch_bounds__(256) void normalize_kernel(
    const float* __restrict__ sig_raw, const float* __restrict__ gamma,
    const float* __restrict__ beta, const double* __restrict__ stats,
    float* __restrict__ sig_norm)
{
    __shared__ float mean_s[9], istd_s[9], gam_s[9], bet_s[9];
    const int tid = threadIdx.x;
    if (tid < 9) {
        double s = 0.0, q = 0.0;
        for (int r = 0; r < NSTAT; ++r) { s += stats[r * 18 + tid]; q += stats[r * 18 + 9 + tid]; }
        const double cnt = (double)Nn * HW;
        const double m = s / cnt;
        const double v = q / cnt - m * m;
        mean_s[tid] = (float)m;
        istd_s[tid] = (float)(1.0 / sqrt(v + (double)BN_EPS_F));
        gam_s[tid] = gamma[tid];
        bet_s[tid] = beta[tid];
    }
    __syncthreads();

    const int p = blockIdx.x * 256 + tid;   // NP = 196 * 256
    float s[9], ssum = 0.f;
#pragma unroll
    for (int k = 0; k < 9; ++k) {
        float v = fmaf((sig_raw[(size_t)k * NP + p] - mean_s[k]) * istd_s[k], gam_s[k], bet_s[k]);
        v = fmaxf(v, CLAMP_MIN_F);
        s[k] = v;
        ssum += v;
    }
    const float inv = 1.f / ssum;
#pragma unroll
    for (int k = 0; k < 9; ++k) sig_norm[(size_t)k * NP + p] = s[k] * inv;
}

// K2: streaming apply — thread per output, 4 chunks/block.
__global__ __launch_bounds__(256) void apply_kernel(
    const float* __restrict__ x, const float* __restrict__ sig_norm,
    float* __restrict__ out)
{
    const int tid = threadIdx.x;
    const int base = blockIdx.x * 1024;
#pragma unroll
    for (int u = 0; u < 4; ++u) {
        const int p = base + u * 256 + tid;
        const int ow = p % OWw;
        const int t1 = p / OWw;
        const int oh = t1 % OHh;
        const int nc = t1 / OHh;
        const int n = nc >> 6;

        const float* xc = x + (size_t)nc * HW;
        const int sb = n * OP + oh * OWw + ow;

        const int r0 = (oh == 0) ? 1 : (2 * oh - 1);
        const int r1 = 2 * oh, r2 = 2 * oh + 1;
        const int c0 = (ow == 0) ? 1 : (2 * ow - 1);
        const int c1 = 2 * ow, c2 = 2 * ow + 1;

        float o = 0.f;
        o = fmaf(sig_norm[0 * NP + sb], xc[r0 * Ww + c0], o);
        o = fmaf(sig_norm[1 * NP + sb], xc[r0 * Ww + c1], o);
        o = fmaf(sig_norm[2 * NP + sb], xc[r0 * Ww + c2], o);
        o = fmaf(sig_norm[3 * NP + sb], xc[r1 * Ww + c0], o);
        o = fmaf(sig_norm[4 * NP + sb], xc[r1 * Ww + c1], o);
        o = fmaf(sig_norm[5 * NP + sb], xc[r1 * Ww + c2], o);
        o = fmaf(sig_norm[6 * NP + sb], xc[r2 * Ww + c0], o);
        o = fmaf(sig_norm[7 * NP + sb], xc[r2 * Ww + c1], o);
        o = fmaf(sig_norm[8 * NP + sb], xc[r2 * Ww + c2], o);
        out[p] = o;
    }
}

} // namespace

extern "C" void kernel_launch(void* const* d_in, const int* in_sizes, int n_in,
                              void* d_out, int out_size, void* d_ws, size_t ws_size,
                              hipStream_t stream) {
    const float* x     = (const float*)d_in[0];
    const float* wgt   = (const float*)d_in[1];
    const float* gamma = (const float*)d_in[2];
    const float* beta  = (const float*)d_in[3];
    float* out = (float*)d_out;

    double* stats   = (double*)d_ws;                                   // NSTAT*18 doubles
    float* sig_raw  = (float*)((char*)d_ws + 4096);                    // 9*NP floats
    float* sig_norm = (float*)((char*)d_ws + 4096 + (size_t)9 * NP * 4);

    hipMemsetAsync(d_ws, 0, 4096, stream);
    conv_stats_sig_kernel<<<dim3(49, 16), 256, 0, stream>>>(x, wgt, stats, sig_raw);
    normalize_kernel<<<NP / 256, 256, 0, stream>>>(sig_raw, gamma, beta, stats, sig_norm);
    apply_kernel<<<(Nn * Cc * OP) / 1024, 256, 0, stream>>>(x, sig_norm, out);
}

// Round 6
// 88.899 us; speedup vs baseline: 1.7611x; 1.6672x over previous
//
#include <hip/hip_runtime.h>
#include <math.h>

namespace {

constexpr int Hh = 112, Ww = 112, Cc = 64, Nn = 16;
constexpr int OHh = 56, OWw = 56;
constexpr int HW = Hh * Ww;            // 12544
constexpr int OP = OHh * OWw;          // 3136
constexpr int NP = Nn * OP;            // 50176
constexpr int NHW = Nn * HW;           // 200704 = 784*256
constexpr float BN_EPS_F = 1e-5f;
constexpr float CLAMP_MIN_F = 1e-4f;
constexpr int TILE_ELEMS = 18 * 18;    // 324
constexpr int NSTAT = 16;

__device__ __forceinline__ int reflect_idx(int t) {
    t = t < 0 ? -t : t;
    t = (t >= Hh) ? (2 * Hh - 2 - t) : t;
    return t;
}

// ---------------- K1: partial conv over 32 channels (R2-exact inner loop).
// Writes full-res partial sums P[half][9][NHW]. No stats, no sigma tail.
__global__ __launch_bounds__(256) void conv_half_kernel(
    const float* __restrict__ x, const float* __restrict__ wgt,
    float* __restrict__ P)
{
    __shared__ float tile[2][TILE_ELEMS];

    const int tid = threadIdx.x;
    const int tx = tid & 15, ty = tid >> 4;
    const int n = blockIdx.y, half = blockIdx.z;
    const int h0 = (int)(blockIdx.x / 7) * 16;
    const int w0 = (int)(blockIdx.x % 7) * 16;

    const int i0 = tid, i1 = tid + 256;
    const bool v1 = (i1 < TILE_ELEMS);
    int g0, g1 = 0;
    {
        const int r = i0 / 18, cl = i0 - r * 18;
        g0 = reflect_idx(h0 - 1 + r) * Ww + reflect_idx(w0 - 1 + cl);
    }
    if (v1) {
        const int r = i1 / 18, cl = i1 - r * 18;
        g1 = reflect_idx(h0 - 1 + r) * Ww + reflect_idx(w0 - 1 + cl);
    }

    const int cbase = half * (Cc / 2);
    const float* xb = x + ((size_t)n * Cc + cbase) * HW;

    tile[0][i0] = xb[g0];
    if (v1) tile[0][i1] = xb[g1];

    float acc[9];
#pragma unroll
    for (int k = 0; k < 9; ++k) acc[k] = 0.f;
    __syncthreads();

    for (int c = 0; c < Cc / 2; ++c) {
        float p0 = 0.f, p1 = 0.f;
        if (c + 1 < Cc / 2) {
            const float* xn = xb + (size_t)(c + 1) * HW;
            p0 = xn[g0];
            if (v1) p1 = xn[g1];
        }
        const float* tl = tile[c & 1];
        float xv[9];
#pragma unroll
        for (int dy = 0; dy < 3; ++dy)
#pragma unroll
            for (int dx = 0; dx < 3; ++dx)
                xv[dy * 3 + dx] = tl[(ty + dy) * 18 + (tx + dx)];
        const int cg = cbase + c;
#pragma unroll
        for (int k = 0; k < 9; ++k) {
            const float* wk = wgt + ((size_t)k * Cc + cg) * 9;
#pragma unroll
            for (int q = 0; q < 9; ++q)
                acc[k] = fmaf(wk[q], xv[q], acc[k]);
        }
        if (c + 1 < Cc / 2) {
            float* td = tile[(c + 1) & 1];
            td[i0] = p0;
            if (v1) td[i1] = p1;
        }
        __syncthreads();
    }

    const int pos = n * HW + (h0 + ty) * Ww + (w0 + tx);
    float* Ph = P + (size_t)half * 9 * NHW;
#pragma unroll
    for (int k = 0; k < 9; ++k) Ph[(size_t)k * NHW + pos] = acc[k];
}

// ---------------- K2: merge halves, accumulate BN stats, extract even positions.
__global__ __launch_bounds__(256) void merge_stats_kernel(
    const float* __restrict__ P, double* __restrict__ stats,
    float* __restrict__ sig_even /* [9][NP] */)
{
    __shared__ float rs[4], rq[4];
    const int tid = threadIdx.x;
    const int k = blockIdx.y;
    const int p = blockIdx.x * 256 + tid;      // NHW = 784*256 exactly

    const float v = P[(size_t)k * NHW + p] + P[(size_t)(9 + k) * NHW + p];

    const int w = p % Ww;
    const int h = (p / Ww) % Hh;
    const int n = p / HW;
    if (!(w & 1) && !(h & 1))
        sig_even[(size_t)k * NP + n * OP + (h >> 1) * OWw + (w >> 1)] = v;

    float s = v, q = v * v;
#pragma unroll
    for (int off = 32; off > 0; off >>= 1) {
        s += __shfl_down(s, off, 64);
        q += __shfl_down(q, off, 64);
    }
    const int lane = tid & 63, wv = tid >> 6;
    if (lane == 0) { rs[wv] = s; rq[wv] = q; }
    __syncthreads();
    if (tid == 0) {
        double* st = stats + (size_t)(blockIdx.x & (NSTAT - 1)) * 18;
        atomicAdd(&st[k], (double)(rs[0] + rs[1] + rs[2] + rs[3]));
        atomicAdd(&st[9 + k], (double)(rq[0] + rq[1] + rq[2] + rq[3]));
    }
}

// ---------------- fallback K1 (small ws): monolithic R2-style conv + stats + even sigma.
__global__ __launch_bounds__(256) void conv_mono_kernel(
    const float* __restrict__ x, const float* __restrict__ wgt,
    double* __restrict__ stats, float* __restrict__ sig_raw /* [9][NP] */)
{
    __shared__ float tile[2][TILE_ELEMS];
    __shared__ float red_sum[4][9], red_sq[4][9];

    const int tid = threadIdx.x;
    const int tx = tid & 15, ty = tid >> 4;
    const int n = blockIdx.y;
    const int h0 = (int)(blockIdx.x / 7) * 16;
    const int w0 = (int)(blockIdx.x % 7) * 16;

    const int i0 = tid, i1 = tid + 256;
    const bool v1 = (i1 < TILE_ELEMS);
    int g0, g1 = 0;
    {
        const int r = i0 / 18, cl = i0 - r * 18;
        g0 = reflect_idx(h0 - 1 + r) * Ww + reflect_idx(w0 - 1 + cl);
    }
    if (v1) {
        const int r = i1 / 18, cl = i1 - r * 18;
        g1 = reflect_idx(h0 - 1 + r) * Ww + reflect_idx(w0 - 1 + cl);
    }

    const float* xb = x + (size_t)n * Cc * HW;
    tile[0][i0] = xb[g0];
    if (v1) tile[0][i1] = xb[g1];

    float acc[9];
#pragma unroll
    for (int k = 0; k < 9; ++k) acc[k] = 0.f;
    __syncthreads();

    for (int c = 0; c < Cc; ++c) {
        float p0 = 0.f, p1 = 0.f;
        if (c + 1 < Cc) {
            const float* xn = xb + (size_t)(c + 1) * HW;
            p0 = xn[g0];
            if (v1) p1 = xn[g1];
        }
        const float* tl = tile[c & 1];
        float xv[9];
#pragma unroll
        for (int dy = 0; dy < 3; ++dy)
#pragma unroll
            for (int dx = 0; dx < 3; ++dx)
                xv[dy * 3 + dx] = tl[(ty + dy) * 18 + (tx + dx)];
#pragma unroll
        for (int k = 0; k < 9; ++k) {
            const float* wk = wgt + ((size_t)k * Cc + c) * 9;
#pragma unroll
            for (int q = 0; q < 9; ++q)
                acc[k] = fmaf(wk[q], xv[q], acc[k]);
        }
        if (c + 1 < Cc) {
            float* td = tile[(c + 1) & 1];
            td[i0] = p0;
            if (v1) td[i1] = p1;
        }
        __syncthreads();
    }

    if (((ty & 1) == 0) && ((tx & 1) == 0)) {
        const int oh = (h0 + ty) >> 1, ow = (w0 + tx) >> 1;
        const int p = n * OP + oh * OWw + ow;
#pragma unroll
        for (int k = 0; k < 9; ++k) sig_raw[(size_t)k * NP + p] = acc[k];
    }

    const int lane = tid & 63;
    const int wv = tid >> 6;
#pragma unroll
    for (int k = 0; k < 9; ++k) {
        float s = acc[k];
        float q = acc[k] * acc[k];
#pragma unroll
        for (int off = 32; off > 0; off >>= 1) {
            s += __shfl_down(s, off, 64);
            q += __shfl_down(q, off, 64);
        }
        if (lane == 0) { red_sum[wv][k] = s; red_sq[wv][k] = q; }
    }
    __syncthreads();
    if (tid < 9) {
        const float s = red_sum[0][tid] + red_sum[1][tid] + red_sum[2][tid] + red_sum[3][tid];
        const float q = red_sq[0][tid] + red_sq[1][tid] + red_sq[2][tid] + red_sq[3][tid];
        double* st = stats + (size_t)((blockIdx.x + 49 * blockIdx.y) & (NSTAT - 1)) * 18;
        atomicAdd(&st[tid], (double)s);
        atomicAdd(&st[9 + tid], (double)q);
    }
}

// ---------------- K3: BN + clamp + tap-normalize per position (tap-major).
__global__ __launch_bounds__(256) void normalize_kernel(
    const float* __restrict__ sig_raw, const float* __restrict__ gamma,
    const float* __restrict__ beta, const double* __restrict__ stats,
    float* __restrict__ sig_norm)
{
    __shared__ float mean_s[9], istd_s[9], gam_s[9], bet_s[9];
    const int tid = threadIdx.x;
    if (tid < 9) {
        double s = 0.0, q = 0.0;
        for (int r = 0; r < NSTAT; ++r) { s += stats[r * 18 + tid]; q += stats[r * 18 + 9 + tid]; }
        const double cnt = (double)Nn * HW;
        const double m = s / cnt;
        const double v = q / cnt - m * m;
        mean_s[tid] = (float)m;
        istd_s[tid] = (float)(1.0 / sqrt(v + (double)BN_EPS_F));
        gam_s[tid] = gamma[tid];
        bet_s[tid] = beta[tid];
    }
    __syncthreads();

    const int p = blockIdx.x * 256 + tid;   // NP = 196 * 256
    float s[9], ssum = 0.f;
#pragma unroll
    for (int k = 0; k < 9; ++k) {
        float v = fmaf((sig_raw[(size_t)k * NP + p] - mean_s[k]) * istd_s[k], gam_s[k], bet_s[k]);
        v = fmaxf(v, CLAMP_MIN_F);
        s[k] = v;
        ssum += v;
    }
    const float inv = 1.f / ssum;
#pragma unroll
    for (int k = 0; k < 9; ++k) sig_norm[(size_t)k * NP + p] = s[k] * inv;
}

// ---------------- K4: streaming apply — thread per output, 4 chunks/block.
__global__ __launch_bounds__(256) void apply_kernel(
    const float* __restrict__ x, const float* __restrict__ sig_norm,
    float* __restrict__ out)
{
    const int tid = threadIdx.x;
    const int base = blockIdx.x * 1024;
#pragma unroll
    for (int u = 0; u < 4; ++u) {
        const int p = base + u * 256 + tid;
        const int ow = p % OWw;
        const int t1 = p / OWw;
        const int oh = t1 % OHh;
        const int nc = t1 / OHh;
        const int n = nc >> 6;

        const float* xc = x + (size_t)nc * HW;
        const int sb = n * OP + oh * OWw + ow;

        const int r0 = (oh == 0) ? 1 : (2 * oh - 1);
        const int r1 = 2 * oh, r2 = 2 * oh + 1;
        const int c0 = (ow == 0) ? 1 : (2 * ow - 1);
        const int c1 = 2 * ow, c2 = 2 * ow + 1;

        float o = 0.f;
        o = fmaf(sig_norm[0 * NP + sb], xc[r0 * Ww + c0], o);
        o = fmaf(sig_norm[1 * NP + sb], xc[r0 * Ww + c1], o);
        o = fmaf(sig_norm[2 * NP + sb], xc[r0 * Ww + c2], o);
        o = fmaf(sig_norm[3 * NP + sb], xc[r1 * Ww + c0], o);
        o = fmaf(sig_norm[4 * NP + sb], xc[r1 * Ww + c1], o);
        o = fmaf(sig_norm[5 * NP + sb], xc[r1 * Ww + c2], o);
        o = fmaf(sig_norm[6 * NP + sb], xc[r2 * Ww + c0], o);
        o = fmaf(sig_norm[7 * NP + sb], xc[r2 * Ww + c1], o);
        o = fmaf(sig_norm[8 * NP + sb], xc[r2 * Ww + c2], o);
        out[p] = o;
    }
}

} // namespace

extern "C" void kernel_launch(void* const* d_in, const int* in_sizes, int n_in,
                              void* d_out, int out_size, void* d_ws, size_t ws_size,
                              hipStream_t stream) {
    const float* x     = (const float*)d_in[0];
    const float* wgt   = (const float*)d_in[1];
    const float* gamma = (const float*)d_in[2];
    const float* beta  = (const float*)d_in[3];
    float* out = (float*)d_out;

    double* stats = (double*)d_ws;                         // NSTAT*18 doubles, in first 4096 B
    hipMemsetAsync(d_ws, 0, 4096, stream);

    const size_t P_bytes   = (size_t)18 * NHW * 4;         // 2 halves x 9 taps x NHW
    const size_t sig_bytes = (size_t)9 * NP * 4;
    const size_t need_big  = 4096 + P_bytes + 2 * sig_bytes;

    if (ws_size >= need_big) {
        float* P        = (float*)((char*)d_ws + 4096);
        float* sig_even = (float*)((char*)d_ws + 4096 + P_bytes);
        float* sig_norm = sig_even + (size_t)9 * NP;

        conv_half_kernel<<<dim3(49, 16, 2), 256, 0, stream>>>(x, wgt, P);
        merge_stats_kernel<<<dim3(NHW / 256, 9), 256, 0, stream>>>(P, stats, sig_even);
        normalize_kernel<<<NP / 256, 256, 0, stream>>>(sig_even, gamma, beta, stats, sig_norm);
        apply_kernel<<<(Nn * Cc * OP) / 1024, 256, 0, stream>>>(x, sig_norm, out);
    } else {
        float* sig_raw  = (float*)((char*)d_ws + 4096);
        float* sig_norm = sig_raw + (size_t)9 * NP;

        conv_mono_kernel<<<dim3(49, 16), 256, 0, stream>>>(x, wgt, stats, sig_raw);
        normalize_kernel<<<NP / 256, 256, 0, stream>>>(sig_raw, gamma, beta, stats, sig_norm);
        apply_kernel<<<(Nn * Cc * OP) / 1024, 256, 0, stream>>>(x, sig_norm, out);
    }
}

// Round 7
// 85.225 us; speedup vs baseline: 1.8371x; 1.0431x over previous
//
#include <hip/hip_runtime.h>
#include <math.h>

namespace {

constexpr int Hh = 112, Ww = 112, Cc = 64, Nn = 16;
constexpr int OHh = 56, OWw = 56;
constexpr int HW = Hh * Ww;            // 12544
constexpr int OP = OHh * OWw;          // 3136
constexpr int NP = Nn * OP;            // 50176
constexpr float BN_EPS_F = 1e-5f;
constexpr float CLAMP_MIN_F = 1e-4f;
constexpr int TP = 24;                 // LDS pitch: row bases {0,24,16,8} mod 32 -> exact 2-way (free)
constexpr int TE = 10 * 18;            // 180 halo elems per channel (8x16 tile)
constexpr int NSTAT = 16;
constexpr int CPW = Cc / 4;            // 16 channels per wave

__device__ __forceinline__ int reflect_idx(int t) {
    t = t < 0 ? -t : t;
    return (t >= Hh) ? (2 * Hh - 2 - t) : t;
}

// K1: conv (64ch -> 9 taps) with channel-split ACROSS WAVES; wave-private
// double-buffered LDS tiles -> NO barrier in the channel loop (global loads
// stay in flight; only wave-local lgkm ordering). End: 2-stage cross-wave
// LDS reduction, even-pixel sigma write (tap-major), stats atomics.
__global__ __launch_bounds__(256) void conv_stats_sig_kernel(
    const float* __restrict__ x, const float* __restrict__ wgt,
    double* __restrict__ stats, float* __restrict__ sig_raw /* [9][NP] */)
{
    __shared__ float tile[4][2][10 * TP];
    __shared__ float red[2][128][9];
    __shared__ float rsum[2][9], rsq[2][9];

    const int tid = threadIdx.x;
    const int lane = tid & 63;
    const int wv = __builtin_amdgcn_readfirstlane(tid >> 6);

    // XCD-aware swizzle: 1568 = 8 * 196 -> each XCD gets a contiguous chunk
    const int f = blockIdx.x;
    const int fs = (f & 7) * 196 + (f >> 3);
    const int t = fs % 98;               // 14(h) x 7(w) tiles of 8x16
    const int n = fs / 98;
    const int h0 = (t / 7) * 8, w0 = (t % 7) * 16;

    // staging map: 180 elems, sets i = lane + 64s, s=0..2 (s=2: lanes < 52)
    int gg[3], ll[3];
#pragma unroll
    for (int s = 0; s < 3; ++s) {
        const int i = lane + 64 * s;
        const int r = i / 18, cl = i - r * 18;
        ll[s] = r * TP + cl;
        gg[s] = reflect_idx(h0 - 1 + r) * Ww + reflect_idx(w0 - 1 + cl);
    }
    const bool v2 = (lane < TE - 128);   // lane < 52

    const float* xw = x + ((size_t)n * Cc + wv * CPW) * HW;
    float* myt0 = &tile[wv][0][0];
    float* myt1 = &tile[wv][1][0];

    // prologue: stage this wave's channel 0 directly
    myt0[ll[0]] = xw[gg[0]];
    myt0[ll[1]] = xw[gg[1]];
    if (v2) myt0[ll[2]] = xw[gg[2]];

    float acc[2][9];
#pragma unroll
    for (int u = 0; u < 2; ++u)
#pragma unroll
        for (int k = 0; k < 9; ++k) acc[u][k] = 0.f;

    const int px = lane & 15, py0 = lane >> 4;   // pixels (py0 + 4u, px), u=0..1

#pragma unroll 2
    for (int c = 0; c < CPW; ++c) {
        // issue next channel's loads (covered by compute below; no vmcnt drain)
        float p0 = 0.f, p1 = 0.f, p2 = 0.f;
        if (c + 1 < CPW) {
            const float* xn = xw + (size_t)(c + 1) * HW;
            p0 = xn[gg[0]];
            p1 = xn[gg[1]];
            if (v2) p2 = xn[gg[2]];
        }

        const float* tl = (c & 1) ? myt1 : myt0;
        float xv[2][9];
#pragma unroll
        for (int u = 0; u < 2; ++u)
#pragma unroll
            for (int dy = 0; dy < 3; ++dy)
#pragma unroll
                for (int dx = 0; dx < 3; ++dx)
                    xv[u][dy * 3 + dx] = tl[(py0 + 4 * u + dy) * TP + (px + dx)];

        const int cg = wv * CPW + c;
#pragma unroll
        for (int k = 0; k < 9; ++k) {
            const float* wk = wgt + ((size_t)k * Cc + cg) * 9;
#pragma unroll
            for (int q = 0; q < 9; ++q) {
                const float w = wk[q];
                acc[0][k] = fmaf(w, xv[0][q], acc[0][k]);
                acc[1][k] = fmaf(w, xv[1][q], acc[1][k]);
            }
        }

        if (c + 1 < CPW) {
            float* td = ((c + 1) & 1) ? myt1 : myt0;
            td[ll[0]] = p0;
            td[ll[1]] = p1;
            if (v2) td[ll[2]] = p2;
        }
    }

    // 2-stage cross-wave reduction: waves 2,3 store slabs; waves 0,1 add.
#pragma unroll
    for (int u = 0; u < 2; ++u) {
        const int pix = (py0 + 4 * u) * 16 + px;
        if (wv >= 2) {
#pragma unroll
            for (int k = 0; k < 9; ++k) red[wv - 2][pix][k] = acc[u][k];
        }
    }
    __syncthreads();
#pragma unroll
    for (int u = 0; u < 2; ++u) {
        const int pix = (py0 + 4 * u) * 16 + px;
        if (wv < 2) {
#pragma unroll
            for (int k = 0; k < 9; ++k) red[wv][pix][k] += acc[u][k];
        }
    }
    __syncthreads();

    // finalize: threads 0..127 own one pixel each
    float sig[9];
    if (tid < 128) {
#pragma unroll
        for (int k = 0; k < 9; ++k) sig[k] = red[0][tid][k] + red[1][tid][k];

        const int pyt = tid >> 4, pxt = tid & 15;
        if (!(pyt & 1) && !(pxt & 1)) {
            const int oh = (h0 + pyt) >> 1, ow = (w0 + pxt) >> 1;
            const int pp = n * OP + oh * OWw + ow;
#pragma unroll
            for (int k = 0; k < 9; ++k) sig_raw[(size_t)k * NP + pp] = sig[k];
        }
    } else {
#pragma unroll
        for (int k = 0; k < 9; ++k) sig[k] = 0.f;
    }

    // stats: shuffle-reduce waves 0,1 -> atomics
#pragma unroll
    for (int k = 0; k < 9; ++k) {
        float s = sig[k], q = sig[k] * sig[k];
#pragma unroll
        for (int off = 32; off > 0; off >>= 1) {
            s += __shfl_down(s, off, 64);
            q += __shfl_down(q, off, 64);
        }
        if (wv < 2 && lane == 0) { rsum[wv][k] = s; rsq[wv][k] = q; }
    }
    __syncthreads();
    if (tid < 9) {
        const float s = rsum[0][tid] + rsum[1][tid];
        const float q = rsq[0][tid] + rsq[1][tid];
        double* st = stats + (size_t)(fs & (NSTAT - 1)) * 18;
        atomicAdd(&st[tid], (double)s);
        atomicAdd(&st[9 + tid], (double)q);
    }
}

// K2: fused normalize + apply. One block per (n, oh) row: BN+clamp+normalize
// the 56-wide sigma row ONCE into LDS, then 4 channels/pass x 16 passes.
__global__ __launch_bounds__(256) void apply_kernel(
    const float* __restrict__ x, const float* __restrict__ sig_raw,
    const float* __restrict__ gamma, const float* __restrict__ beta,
    const double* __restrict__ stats, float* __restrict__ out)
{
    __shared__ float srow[9][OWw];
    __shared__ float mean_s[9], istd_s[9], gb[18];

    const int tid = threadIdx.x;
    // swizzle: 896 = 8 * 112
    const int f = blockIdx.x;
    const int fs = (f & 7) * 112 + (f >> 3);
    const int n = fs / OHh;
    const int oh = fs % OHh;

    if (tid < 9) {
        double s = 0.0, q = 0.0;
        for (int r = 0; r < NSTAT; ++r) { s += stats[r * 18 + tid]; q += stats[r * 18 + 9 + tid]; }
        const double cnt = (double)Nn * HW;
        const double m = s / cnt;
        const double v = q / cnt - m * m;
        mean_s[tid] = (float)m;
        istd_s[tid] = (float)(1.0 / sqrt(v + (double)BN_EPS_F));
        gb[tid] = gamma[tid];
        gb[9 + tid] = beta[tid];
    }
    __syncthreads();

    if (tid < OWw) {
        const int pp = n * OP + oh * OWw + tid;
        float s[9], ssum = 0.f;
#pragma unroll
        for (int k = 0; k < 9; ++k) {
            float v = fmaf((sig_raw[(size_t)k * NP + pp] - mean_s[k]) * istd_s[k], gb[k], gb[9 + k]);
            v = fmaxf(v, CLAMP_MIN_F);
            s[k] = v;
            ssum += v;
        }
        const float inv = 1.f / ssum;
#pragma unroll
        for (int k = 0; k < 9; ++k) srow[k][tid] = s[k] * inv;
    }
    __syncthreads();

    const int csub = tid >> 6;           // wave-uniform channel sub-index
    const int lane = tid & 63;
    if (lane >= OWw) return;             // no barriers after this point
    const int ow = lane;

    const int r0 = (oh == 0) ? 1 : (2 * oh - 1);
    const int r1 = 2 * oh, r2 = 2 * oh + 1;
    const int c0 = (ow == 0) ? 1 : (2 * ow - 1);
    const int c1 = 2 * ow, c2 = 2 * ow + 1;

    float sg[9];
#pragma unroll
    for (int k = 0; k < 9; ++k) sg[k] = srow[k][ow];

#pragma unroll 2
    for (int cc = 0; cc < 16; ++cc) {
        const int c = cc * 4 + csub;
        const float* xc = x + ((size_t)(n * Cc + c)) * HW;
        float o = 0.f;
        o = fmaf(sg[0], xc[r0 * Ww + c0], o);
        o = fmaf(sg[1], xc[r0 * Ww + c1], o);
        o = fmaf(sg[2], xc[r0 * Ww + c2], o);
        o = fmaf(sg[3], xc[r1 * Ww + c0], o);
        o = fmaf(sg[4], xc[r1 * Ww + c1], o);
        o = fmaf(sg[5], xc[r1 * Ww + c2], o);
        o = fmaf(sg[6], xc[r2 * Ww + c0], o);
        o = fmaf(sg[7], xc[r2 * Ww + c1], o);
        o = fmaf(sg[8], xc[r2 * Ww + c2], o);
        out[((size_t)(n * Cc + c)) * OP + oh * OWw + ow] = o;
    }
}

} // namespace

extern "C" void kernel_launch(void* const* d_in, const int* in_sizes, int n_in,
                              void* d_out, int out_size, void* d_ws, size_t ws_size,
                              hipStream_t stream) {
    const float* x     = (const float*)d_in[0];
    const float* wgt   = (const float*)d_in[1];
    const float* gamma = (const float*)d_in[2];
    const float* beta  = (const float*)d_in[3];
    float* out = (float*)d_out;

    double* stats  = (double*)d_ws;                      // NSTAT*18 doubles (2304 B)
    float* sig_raw = (float*)((char*)d_ws + 4096);       // 9*NP floats = 1.81 MB

    hipMemsetAsync(d_ws, 0, 4096, stream);
    conv_stats_sig_kernel<<<1568, 256, 0, stream>>>(x, wgt, stats, sig_raw);
    apply_kernel<<<896, 256, 0, stream>>>(x, sig_raw, gamma, beta, stats, out);
}

// Round 8
// 82.734 us; speedup vs baseline: 1.8924x; 1.0301x over previous
//
#include <hip/hip_runtime.h>
#include <math.h>

namespace {

constexpr int Hh = 112, Ww = 112, Cc = 64, Nn = 16;
constexpr int OHh = 56, OWw = 56;
constexpr int HW = Hh * Ww;            // 12544 = 49*256
constexpr int OP = OHh * OWw;          // 3136
constexpr int NP = Nn * OP;            // 50176
constexpr int NHW = Nn * HW;           // 200704 = 784*256
constexpr float BN_EPS_F = 1e-5f;
constexpr float CLAMP_MIN_F = 1e-4f;
constexpr int NSTAT = 32;
constexpr int CH = 32;                 // channels per half

// K1: direct-load conv — NO LDS, NO barriers. Each lane owns one pixel; 9
// window offsets precomputed (reflect folded in); channel loop advances a
// wave-uniform base (saddr-form loads, zero per-iter addressing VALU).
// 1-deep register prefetch. Writes partial sums P[half][9][NHW].
__global__ __launch_bounds__(256) void conv_half_kernel(
    const float* __restrict__ x, const float* __restrict__ wgt,
    float* __restrict__ P)
{
    const int tid = threadIdx.x;
    const int b = blockIdx.x;                    // 1568 = 8*196
    const int swz = (b & 7) * 196 + (b >> 3);    // XCD-contiguous chunks
    const int half = swz / 784;
    const int bid = swz - half * 784;

    const int pos = bid * 256 + tid;             // n-aligned: HW = 49*256
    const int n = bid / 49;
    const int hw = pos - n * HW;
    const int h = hw / Ww, w = hw - h * Ww;

    const int hm = (h == 0) ? 1 : (h - 1);
    const int hp = (h == Hh - 1) ? (Hh - 2) : (h + 1);
    const int wm = (w == 0) ? 1 : (w - 1);
    const int wp = (w == Ww - 1) ? (Ww - 2) : (w + 1);
    const int r0 = hm * Ww, r1 = h * Ww, r2 = hp * Ww;

    int off[9];
    off[0] = r0 + wm; off[1] = r0 + w; off[2] = r0 + wp;
    off[3] = r1 + wm; off[4] = r1 + w; off[5] = r1 + wp;
    off[6] = r2 + wm; off[7] = r2 + w; off[8] = r2 + wp;

    const float* xb = x + ((size_t)n * Cc + half * CH) * HW;

    float cur[9], nxt[9], acc[9];
#pragma unroll
    for (int j = 0; j < 9; ++j) { cur[j] = xb[off[j]]; acc[j] = 0.f; }

#pragma unroll 2
    for (int c = 0; c < CH; ++c) {
        // prefetch channel c+1 (wraps to c=0 on last iter: in-bounds, unused)
        const float* xn = xb + (size_t)((c + 1) & (CH - 1)) * HW;
#pragma unroll
        for (int j = 0; j < 9; ++j) nxt[j] = xn[off[j]];

        const int cg = half * CH + c;
#pragma unroll
        for (int k = 0; k < 9; ++k) {
            const float* wk = wgt + ((size_t)k * Cc + cg) * 9;   // uniform -> s_load
#pragma unroll
            for (int q = 0; q < 9; ++q)
                acc[k] = fmaf(wk[q], cur[q], acc[k]);
        }
#pragma unroll
        for (int j = 0; j < 9; ++j) cur[j] = nxt[j];
    }

    float* Ph = P + (size_t)half * 9 * NHW;
#pragma unroll
    for (int k = 0; k < 9; ++k) Ph[(size_t)k * NHW + pos] = acc[k];
}

// K2: merge halves, accumulate BN stats (spread atomics), extract even positions.
__global__ __launch_bounds__(256) void merge_stats_kernel(
    const float* __restrict__ P, double* __restrict__ stats,
    float* __restrict__ sig_even /* [9][NP] */)
{
    __shared__ float rs[4], rq[4];
    const int tid = threadIdx.x;
    const int k = blockIdx.y;
    const int p = blockIdx.x * 256 + tid;        // NHW = 784*256

    const float v = P[(size_t)k * NHW + p] + P[(size_t)(9 + k) * NHW + p];

    const int w = p % Ww;
    const int h = (p / Ww) % Hh;
    const int n = p / HW;
    if (!(w & 1) && !(h & 1))
        sig_even[(size_t)k * NP + n * OP + (h >> 1) * OWw + (w >> 1)] = v;

    float s = v, q = v * v;
#pragma unroll
    for (int off = 32; off > 0; off >>= 1) {
        s += __shfl_down(s, off, 64);
        q += __shfl_down(q, off, 64);
    }
    const int lane = tid & 63, wv = tid >> 6;
    if (lane == 0) { rs[wv] = s; rq[wv] = q; }
    __syncthreads();
    if (tid == 0) {
        double* st = stats + (size_t)(blockIdx.x & (NSTAT - 1)) * 18;
        atomicAdd(&st[k], (double)(rs[0] + rs[1] + rs[2] + rs[3]));
        atomicAdd(&st[9 + k], (double)(rq[0] + rq[1] + rq[2] + rq[3]));
    }
}

// K3: fused normalize + apply. One block per (n, oh) row: BN+clamp+normalize
// the 56-wide sigma row ONCE into LDS, then 4 channels/pass x 16 passes.
__global__ __launch_bounds__(256) void apply_kernel(
    const float* __restrict__ x, const float* __restrict__ sig_raw,
    const float* __restrict__ gamma, const float* __restrict__ beta,
    const double* __restrict__ stats, float* __restrict__ out)
{
    __shared__ float srow[9][OWw];
    __shared__ float mean_s[9], istd_s[9], gb[18];

    const int tid = threadIdx.x;
    const int f = blockIdx.x;                    // 896 = 8*112
    const int fs = (f & 7) * 112 + (f >> 3);
    const int n = fs / OHh;
    const int oh = fs % OHh;

    if (tid < 9) {
        double s = 0.0, q = 0.0;
        for (int r = 0; r < NSTAT; ++r) { s += stats[r * 18 + tid]; q += stats[r * 18 + 9 + tid]; }
        const double cnt = (double)Nn * HW;
        const double m = s / cnt;
        const double v = q / cnt - m * m;
        mean_s[tid] = (float)m;
        istd_s[tid] = (float)(1.0 / sqrt(v + (double)BN_EPS_F));
        gb[tid] = gamma[tid];
        gb[9 + tid] = beta[tid];
    }
    __syncthreads();

    if (tid < OWw) {
        const int pp = n * OP + oh * OWw + tid;
        float s[9], ssum = 0.f;
#pragma unroll
        for (int k = 0; k < 9; ++k) {
            float v = fmaf((sig_raw[(size_t)k * NP + pp] - mean_s[k]) * istd_s[k], gb[k], gb[9 + k]);
            v = fmaxf(v, CLAMP_MIN_F);
            s[k] = v;
            ssum += v;
        }
        const float inv = 1.f / ssum;
#pragma unroll
        for (int k = 0; k < 9; ++k) srow[k][tid] = s[k] * inv;
    }
    __syncthreads();

    const int csub = tid >> 6;                   // wave-uniform channel sub-index
    const int lane = tid & 63;
    if (lane >= OWw) return;                     // no barriers after this point
    const int ow = lane;

    const int r0 = (oh == 0) ? 1 : (2 * oh - 1);
    const int r1 = 2 * oh, r2 = 2 * oh + 1;
    const int c0 = (ow == 0) ? 1 : (2 * ow - 1);
    const int c1 = 2 * ow, c2 = 2 * ow + 1;

    float sg[9];
#pragma unroll
    for (int k = 0; k < 9; ++k) sg[k] = srow[k][ow];

#pragma unroll 2
    for (int cc = 0; cc < 16; ++cc) {
        const int c = cc * 4 + csub;
        const float* xc = x + ((size_t)(n * Cc + c)) * HW;
        float o = 0.f;
        o = fmaf(sg[0], xc[r0 * Ww + c0], o);
        o = fmaf(sg[1], xc[r0 * Ww + c1], o);
        o = fmaf(sg[2], xc[r0 * Ww + c2], o);
        o = fmaf(sg[3], xc[r1 * Ww + c0], o);
        o = fmaf(sg[4], xc[r1 * Ww + c1], o);
        o = fmaf(sg[5], xc[r1 * Ww + c2], o);
        o = fmaf(sg[6], xc[r2 * Ww + c0], o);
        o = fmaf(sg[7], xc[r2 * Ww + c1], o);
        o = fmaf(sg[8], xc[r2 * Ww + c2], o);
        out[((size_t)(n * Cc + c)) * OP + oh * OWw + ow] = o;
    }
}

} // namespace

extern "C" void kernel_launch(void* const* d_in, const int* in_sizes, int n_in,
                              void* d_out, int out_size, void* d_ws, size_t ws_size,
                              hipStream_t stream) {
    const float* x     = (const float*)d_in[0];
    const float* wgt   = (const float*)d_in[1];
    const float* gamma = (const float*)d_in[2];
    const float* beta  = (const float*)d_in[3];
    float* out = (float*)d_out;

    double* stats = (double*)d_ws;                           // NSTAT*18 doubles = 4608 B
    float* P        = (float*)((char*)d_ws + 8192);          // 18*NHW floats = 14.45 MB
    float* sig_even = P + (size_t)18 * NHW;                  // 9*NP floats = 1.81 MB

    hipMemsetAsync(d_ws, 0, 8192, stream);
    conv_half_kernel<<<1568, 256, 0, stream>>>(x, wgt, P);
    merge_stats_kernel<<<dim3(NHW / 256, 9), 256, 0, stream>>>(P, stats, sig_even);
    apply_kernel<<<896, 256, 0, stream>>>(x, sig_even, gamma, beta, stats, out);
}

// Round 9
// 76.030 us; speedup vs baseline: 2.0592x; 1.0882x over previous
//
#include <hip/hip_runtime.h>
#include <math.h>

namespace {

constexpr int Hh = 112, Ww = 112, Cc = 64, Nn = 16;
constexpr int OHh = 56, OWw = 56;
constexpr int HW = Hh * Ww;            // 12544 = 49*256
constexpr int OP = OHh * OWw;          // 3136
constexpr int NP = Nn * OP;            // 50176
constexpr int NHW = Nn * HW;           // 200704 = 784*256
constexpr float BN_EPS_F = 1e-5f;
constexpr float CLAMP_MIN_F = 1e-4f;
constexpr int NSTAT = 32;
constexpr int CH = 32;                 // channels per half

// K1: direct-load conv, 1x2 pixel strip per lane — no LDS, no barriers.
// Window = 3 rows x 4 cols: per row one aligned float2 + 2 edge dwords
// -> 9 VMEM instrs / 2 pixels / channel (halved), 162 FMAs per iter
// (doubled latency cover). 1-deep register prefetch; channel loop advances
// a wave-uniform base. Writes partial sums P[half][9][NHW] as float2.
__global__ __launch_bounds__(256) void conv_half_kernel(
    const float* __restrict__ x, const float* __restrict__ wgt,
    float* __restrict__ P)
{
    const int tid = threadIdx.x;
    const int b = blockIdx.x;                    // 784 = 8*98
    const int swz = (b & 7) * 98 + (b >> 3);     // XCD chunk = 4 n-planes of one half
    const int half = swz / 392;
    const int bid = swz - half * 392;

    const int s = bid * 256 + tid;               // strip id; pixels 2s, 2s+1
    const int pos0 = 2 * s;
    const int n = pos0 / HW;
    const int hw = pos0 - n * HW;
    const int h = hw / Ww;
    const int w0 = hw - h * Ww;                  // even, 0..110

    const int hm = (h == 0) ? 1 : h - 1;
    const int hp = (h == Hh - 1) ? (Hh - 2) : (h + 1);
    const int wl = (w0 == 0) ? 1 : w0 - 1;
    const int wr = (w0 == Ww - 2) ? (Ww - 2) : (w0 + 2);

    const int ro[3] = { hm * Ww, h * Ww, hp * Ww };

    const float* xb = x + ((size_t)n * Cc + half * CH) * HW;

    float m0[3], m1[3], el[3], er[3];            // window: [el, m0, m1, er] x 3 rows
    float n_m0[3], n_m1[3], n_el[3], n_er[3];
#pragma unroll
    for (int r = 0; r < 3; ++r) {
        const float2 f2 = *(const float2*)(xb + ro[r] + w0);
        m0[r] = f2.x; m1[r] = f2.y;
        el[r] = xb[ro[r] + wl];
        er[r] = xb[ro[r] + wr];
    }

    float acc0[9], acc1[9];
#pragma unroll
    for (int k = 0; k < 9; ++k) { acc0[k] = 0.f; acc1[k] = 0.f; }

#pragma unroll 2
    for (int c = 0; c < CH; ++c) {
        // prefetch channel c+1 (wraps on last iter: in-bounds, unused)
        const float* xn = xb + (size_t)((c + 1) & (CH - 1)) * HW;
#pragma unroll
        for (int r = 0; r < 3; ++r) {
            const float2 f2 = *(const float2*)(xn + ro[r] + w0);
            n_m0[r] = f2.x; n_m1[r] = f2.y;
            n_el[r] = xn[ro[r] + wl];
            n_er[r] = xn[ro[r] + wr];
        }

        const int cg = half * CH + c;
#pragma unroll
        for (int k = 0; k < 9; ++k) {
            const float* wk = wgt + ((size_t)k * Cc + cg) * 9;   // uniform -> s_load
#pragma unroll
            for (int r = 0; r < 3; ++r) {
                const float wa = wk[3 * r], wb = wk[3 * r + 1], wc = wk[3 * r + 2];
                acc0[k] = fmaf(wa, el[r], acc0[k]);
                acc0[k] = fmaf(wb, m0[r], acc0[k]);
                acc0[k] = fmaf(wc, m1[r], acc0[k]);
                acc1[k] = fmaf(wa, m0[r], acc1[k]);
                acc1[k] = fmaf(wb, m1[r], acc1[k]);
                acc1[k] = fmaf(wc, er[r], acc1[k]);
            }
        }

#pragma unroll
        for (int r = 0; r < 3; ++r) {
            m0[r] = n_m0[r]; m1[r] = n_m1[r];
            el[r] = n_el[r]; er[r] = n_er[r];
        }
    }

    float* Ph = P + (size_t)half * 9 * NHW;
#pragma unroll
    for (int k = 0; k < 9; ++k)
        *(float2*)(Ph + (size_t)k * NHW + pos0) = make_float2(acc0[k], acc1[k]);
}

// K2: merge halves, accumulate BN stats (spread atomics), extract even positions.
__global__ __launch_bounds__(256) void merge_stats_kernel(
    const float* __restrict__ P, double* __restrict__ stats,
    float* __restrict__ sig_even /* [9][NP] */)
{
    __shared__ float rs[4], rq[4];
    const int tid = threadIdx.x;
    const int k = blockIdx.y;
    const int p = blockIdx.x * 256 + tid;        // NHW = 784*256

    const float v = P[(size_t)k * NHW + p] + P[(size_t)(9 + k) * NHW + p];

    const int w = p % Ww;
    const int h = (p / Ww) % Hh;
    const int n = p / HW;
    if (!(w & 1) && !(h & 1))
        sig_even[(size_t)k * NP + n * OP + (h >> 1) * OWw + (w >> 1)] = v;

    float s = v, q = v * v;
#pragma unroll
    for (int off = 32; off > 0; off >>= 1) {
        s += __shfl_down(s, off, 64);
        q += __shfl_down(q, off, 64);
    }
    const int lane = tid & 63, wv = tid >> 6;
    if (lane == 0) { rs[wv] = s; rq[wv] = q; }
    __syncthreads();
    if (tid == 0) {
        double* st = stats + (size_t)(blockIdx.x & (NSTAT - 1)) * 18;
        atomicAdd(&st[k], (double)(rs[0] + rs[1] + rs[2] + rs[3]));
        atomicAdd(&st[9 + k], (double)(rq[0] + rq[1] + rq[2] + rq[3]));
    }
}

// K3: fused normalize + apply. One block per (n, oh) row: BN+clamp+normalize
// the 56-wide sigma row ONCE into LDS, then 4 channels/pass x 16 passes.
__global__ __launch_bounds__(256) void apply_kernel(
    const float* __restrict__ x, const float* __restrict__ sig_raw,
    const float* __restrict__ gamma, const float* __restrict__ beta,
    const double* __restrict__ stats, float* __restrict__ out)
{
    __shared__ float srow[9][OWw];
    __shared__ float mean_s[9], istd_s[9], gb[18];

    const int tid = threadIdx.x;
    const int f = blockIdx.x;                    // 896 = 8*112
    const int fs = (f & 7) * 112 + (f >> 3);
    const int n = fs / OHh;
    const int oh = fs % OHh;

    if (tid < 9) {
        double s = 0.0, q = 0.0;
        for (int r = 0; r < NSTAT; ++r) { s += stats[r * 18 + tid]; q += stats[r * 18 + 9 + tid]; }
        const double cnt = (double)Nn * HW;
        const double m = s / cnt;
        const double v = q / cnt - m * m;
        mean_s[tid] = (float)m;
        istd_s[tid] = (float)(1.0 / sqrt(v + (double)BN_EPS_F));
        gb[tid] = gamma[tid];
        gb[9 + tid] = beta[tid];
    }
    __syncthreads();

    if (tid < OWw) {
        const int pp = n * OP + oh * OWw + tid;
        float s[9], ssum = 0.f;
#pragma unroll
        for (int k = 0; k < 9; ++k) {
            float v = fmaf((sig_raw[(size_t)k * NP + pp] - mean_s[k]) * istd_s[k], gb[k], gb[9 + k]);
            v = fmaxf(v, CLAMP_MIN_F);
            s[k] = v;
            ssum += v;
        }
        const float inv = 1.f / ssum;
#pragma unroll
        for (int k = 0; k < 9; ++k) srow[k][tid] = s[k] * inv;
    }
    __syncthreads();

    const int csub = tid >> 6;                   // wave-uniform channel sub-index
    const int lane = tid & 63;
    if (lane >= OWw) return;                     // no barriers after this point
    const int ow = lane;

    const int r0 = (oh == 0) ? 1 : (2 * oh - 1);
    const int r1 = 2 * oh, r2 = 2 * oh + 1;
    const int c0 = (ow == 0) ? 1 : (2 * ow - 1);
    const int c1 = 2 * ow, c2 = 2 * ow + 1;

    float sg[9];
#pragma unroll
    for (int k = 0; k < 9; ++k) sg[k] = srow[k][ow];

#pragma unroll 2
    for (int cc = 0; cc < 16; ++cc) {
        const int c = cc * 4 + csub;
        const float* xc = x + ((size_t)(n * Cc + c)) * HW;
        float o = 0.f;
        o = fmaf(sg[0], xc[r0 * Ww + c0], o);
        o = fmaf(sg[1], xc[r0 * Ww + c1], o);
        o = fmaf(sg[2], xc[r0 * Ww + c2], o);
        o = fmaf(sg[3], xc[r1 * Ww + c0], o);
        o = fmaf(sg[4], xc[r1 * Ww + c1], o);
        o = fmaf(sg[5], xc[r1 * Ww + c2], o);
        o = fmaf(sg[6], xc[r2 * Ww + c0], o);
        o = fmaf(sg[7], xc[r2 * Ww + c1], o);
        o = fmaf(sg[8], xc[r2 * Ww + c2], o);
        out[((size_t)(n * Cc + c)) * OP + oh * OWw + ow] = o;
    }
}

} // namespace

extern "C" void kernel_launch(void* const* d_in, const int* in_sizes, int n_in,
                              void* d_out, int out_size, void* d_ws, size_t ws_size,
                              hipStream_t stream) {
    const float* x     = (const float*)d_in[0];
    const float* wgt   = (const float*)d_in[1];
    const float* gamma = (const float*)d_in[2];
    const float* beta  = (const float*)d_in[3];
    float* out = (float*)d_out;

    double* stats = (double*)d_ws;                           // NSTAT*18 doubles = 4608 B
    float* P        = (float*)((char*)d_ws + 8192);          // 18*NHW floats = 14.45 MB
    float* sig_even = P + (size_t)18 * NHW;                  // 9*NP floats = 1.81 MB

    hipMemsetAsync(d_ws, 0, 8192, stream);
    conv_half_kernel<<<784, 256, 0, stream>>>(x, wgt, P);
    merge_stats_kernel<<<dim3(NHW / 256, 9), 256, 0, stream>>>(P, stats, sig_even);
    apply_kernel<<<896, 256, 0, stream>>>(x, sig_even, gamma, beta, stats, out);
}

// Round 10
// 71.424 us; speedup vs baseline: 2.1920x; 1.0645x over previous
//
#include <hip/hip_runtime.h>
#include <math.h>

namespace {

constexpr int Hh = 112, Ww = 112, Cc = 64, Nn = 16;
constexpr int OHh = 56, OWw = 56;
constexpr int HW = Hh * Ww;            // 12544 = 49*256
constexpr int OP = OHh * OWw;          // 3136
constexpr int NP = Nn * OP;            // 50176
constexpr int NHW = Nn * HW;           // 200704 = 784*256 = 196*1024
constexpr float BN_EPS_F = 1e-5f;
constexpr float CLAMP_MIN_F = 1e-4f;
constexpr int NSTAT = 32;

// K1: direct-load conv, 1x2 pixel strip per lane — no LDS, no barriers.
// R9-proven inner loop; channel range split NSPLIT ways across blocks to
// restore occupancy (NSPLIT=4 -> 1568 blocks ~ 24 waves/CU).
template <int NSPLIT>
__global__ __launch_bounds__(256) void conv_split_kernel(
    const float* __restrict__ x, const float* __restrict__ wgt,
    float* __restrict__ P /* [NSPLIT][9][NHW] */)
{
    constexpr int CHS = Cc / NSPLIT;               // channels per part
    constexpr int NBLK = NSPLIT * 392;

    const int tid = threadIdx.x;
    const int b = blockIdx.x;
    const int swz = (b & 7) * (NBLK / 8) + (b >> 3);   // XCD-contiguous chunks
    const int part = swz / 392;
    const int bid = swz - part * 392;

    const int s = bid * 256 + tid;                 // strip id; pixels 2s, 2s+1
    const int pos0 = 2 * s;
    const int n = pos0 / HW;
    const int hw = pos0 - n * HW;
    const int h = hw / Ww;
    const int w0 = hw - h * Ww;                    // even, 0..110 (row-aligned)

    const int hm = (h == 0) ? 1 : h - 1;
    const int hp = (h == Hh - 1) ? (Hh - 2) : (h + 1);
    const int wl = (w0 == 0) ? 1 : w0 - 1;
    const int wr = (w0 == Ww - 2) ? (Ww - 2) : (w0 + 2);

    const int ro[3] = { hm * Ww, h * Ww, hp * Ww };

    const float* xb = x + ((size_t)n * Cc + part * CHS) * HW;

    float m0[3], m1[3], el[3], er[3];              // window: [el, m0, m1, er] x 3 rows
    float n_m0[3], n_m1[3], n_el[3], n_er[3];
#pragma unroll
    for (int r = 0; r < 3; ++r) {
        const float2 f2 = *(const float2*)(xb + ro[r] + w0);
        m0[r] = f2.x; m1[r] = f2.y;
        el[r] = xb[ro[r] + wl];
        er[r] = xb[ro[r] + wr];
    }

    float acc0[9], acc1[9];
#pragma unroll
    for (int k = 0; k < 9; ++k) { acc0[k] = 0.f; acc1[k] = 0.f; }

#pragma unroll 2
    for (int c = 0; c < CHS; ++c) {
        // prefetch channel c+1 (wraps on last iter: in-bounds, unused)
        const float* xn = xb + (size_t)((c + 1) & (CHS - 1)) * HW;
#pragma unroll
        for (int r = 0; r < 3; ++r) {
            const float2 f2 = *(const float2*)(xn + ro[r] + w0);
            n_m0[r] = f2.x; n_m1[r] = f2.y;
            n_el[r] = xn[ro[r] + wl];
            n_er[r] = xn[ro[r] + wr];
        }

        const int cg = part * CHS + c;
#pragma unroll
        for (int k = 0; k < 9; ++k) {
            const float* wk = wgt + ((size_t)k * Cc + cg) * 9;   // uniform -> s_load
#pragma unroll
            for (int r = 0; r < 3; ++r) {
                const float wa = wk[3 * r], wb = wk[3 * r + 1], wc = wk[3 * r + 2];
                acc0[k] = fmaf(wa, el[r], acc0[k]);
                acc0[k] = fmaf(wb, m0[r], acc0[k]);
                acc0[k] = fmaf(wc, m1[r], acc0[k]);
                acc1[k] = fmaf(wa, m0[r], acc1[k]);
                acc1[k] = fmaf(wb, m1[r], acc1[k]);
                acc1[k] = fmaf(wc, er[r], acc1[k]);
            }
        }

#pragma unroll
        for (int r = 0; r < 3; ++r) {
            m0[r] = n_m0[r]; m1[r] = n_m1[r];
            el[r] = n_el[r]; er[r] = n_er[r];
        }
    }

    float* Ph = P + (size_t)part * 9 * NHW;
#pragma unroll
    for (int k = 0; k < 9; ++k)
        *(float2*)(Ph + (size_t)k * NHW + pos0) = make_float2(acc0[k], acc1[k]);
}

// K2: merge NSPLIT partials (float4/lane = 4 px), BN stats (spread atomics),
// extract even positions (aligned float2 stores).
template <int NSPLIT>
__global__ __launch_bounds__(256) void merge_stats_kernel(
    const float* __restrict__ P, double* __restrict__ stats,
    float* __restrict__ sig_even /* [9][NP] */)
{
    __shared__ float rs[4], rq[4];
    const int tid = threadIdx.x;
    const int k = blockIdx.y;
    const int p0 = (blockIdx.x * 256 + tid) * 4;   // NHW = 196*1024

    float4 v = *(const float4*)(P + (size_t)k * NHW + p0);
#pragma unroll
    for (int qq = 1; qq < NSPLIT; ++qq) {
        const float4 t = *(const float4*)(P + ((size_t)qq * 9 + k) * NHW + p0);
        v.x += t.x; v.y += t.y; v.z += t.z; v.w += t.w;
    }

    const int w = p0 % Ww;                         // multiple of 4
    const int h = (p0 / Ww) % Hh;
    const int n = p0 / HW;
    if (!(h & 1)) {
        // even pixels are .x (w) and .z (w+2) -> consecutive sig_even slots
        *(float2*)(sig_even + (size_t)k * NP + n * OP + (h >> 1) * OWw + (w >> 1)) =
            make_float2(v.x, v.z);
    }

    float s = v.x + v.y + v.z + v.w;
    float q = v.x * v.x + v.y * v.y + v.z * v.z + v.w * v.w;
#pragma unroll
    for (int off = 32; off > 0; off >>= 1) {
        s += __shfl_down(s, off, 64);
        q += __shfl_down(q, off, 64);
    }
    const int lane = tid & 63, wv = tid >> 6;
    if (lane == 0) { rs[wv] = s; rq[wv] = q; }
    __syncthreads();
    if (tid == 0) {
        double* st = stats + (size_t)(blockIdx.x & (NSTAT - 1)) * 18;
        atomicAdd(&st[k], (double)(rs[0] + rs[1] + rs[2] + rs[3]));
        atomicAdd(&st[9 + k], (double)(rq[0] + rq[1] + rq[2] + rq[3]));
    }
}

// K3: fused normalize + apply. One block per (n, oh) row: BN+clamp+normalize
// the 56-wide sigma row ONCE into LDS, then 4 channels/pass x 16 passes.
__global__ __launch_bounds__(256) void apply_kernel(
    const float* __restrict__ x, const float* __restrict__ sig_raw,
    const float* __restrict__ gamma, const float* __restrict__ beta,
    const double* __restrict__ stats, float* __restrict__ out)
{
    __shared__ float srow[9][OWw];
    __shared__ float mean_s[9], istd_s[9], gb[18];

    const int tid = threadIdx.x;
    const int f = blockIdx.x;                      // 896 = 8*112
    const int fs = (f & 7) * 112 + (f >> 3);
    const int n = fs / OHh;
    const int oh = fs % OHh;

    if (tid < 9) {
        double s = 0.0, q = 0.0;
        for (int r = 0; r < NSTAT; ++r) { s += stats[r * 18 + tid]; q += stats[r * 18 + 9 + tid]; }
        const double cnt = (double)Nn * HW;
        const double m = s / cnt;
        const double v = q / cnt - m * m;
        mean_s[tid] = (float)m;
        istd_s[tid] = (float)(1.0 / sqrt(v + (double)BN_EPS_F));
        gb[tid] = gamma[tid];
        gb[9 + tid] = beta[tid];
    }
    __syncthreads();

    if (tid < OWw) {
        const int pp = n * OP + oh * OWw + tid;
        float s[9], ssum = 0.f;
#pragma unroll
        for (int k = 0; k < 9; ++k) {
            float v = fmaf((sig_raw[(size_t)k * NP + pp] - mean_s[k]) * istd_s[k], gb[k], gb[9 + k]);
            v = fmaxf(v, CLAMP_MIN_F);
            s[k] = v;
            ssum += v;
        }
        const float inv = 1.f / ssum;
#pragma unroll
        for (int k = 0; k < 9; ++k) srow[k][tid] = s[k] * inv;
    }
    __syncthreads();

    const int csub = tid >> 6;                     // wave-uniform channel sub-index
    const int lane = tid & 63;
    if (lane >= OWw) return;                       // no barriers after this point
    const int ow = lane;

    const int r0 = (oh == 0) ? 1 : (2 * oh - 1);
    const int r1 = 2 * oh, r2 = 2 * oh + 1;
    const int c0 = (ow == 0) ? 1 : (2 * ow - 1);
    const int c1 = 2 * ow, c2 = 2 * ow + 1;

    float sg[9];
#pragma unroll
    for (int k = 0; k < 9; ++k) sg[k] = srow[k][ow];

#pragma unroll 2
    for (int cc = 0; cc < 16; ++cc) {
        const int c = cc * 4 + csub;
        const float* xc = x + ((size_t)(n * Cc + c)) * HW;
        float o = 0.f;
        o = fmaf(sg[0], xc[r0 * Ww + c0], o);
        o = fmaf(sg[1], xc[r0 * Ww + c1], o);
        o = fmaf(sg[2], xc[r0 * Ww + c2], o);
        o = fmaf(sg[3], xc[r1 * Ww + c0], o);
        o = fmaf(sg[4], xc[r1 * Ww + c1], o);
        o = fmaf(sg[5], xc[r1 * Ww + c2], o);
        o = fmaf(sg[6], xc[r2 * Ww + c0], o);
        o = fmaf(sg[7], xc[r2 * Ww + c1], o);
        o = fmaf(sg[8], xc[r2 * Ww + c2], o);
        out[((size_t)(n * Cc + c)) * OP + oh * OWw + ow] = o;
    }
}

} // namespace

extern "C" void kernel_launch(void* const* d_in, const int* in_sizes, int n_in,
                              void* d_out, int out_size, void* d_ws, size_t ws_size,
                              hipStream_t stream) {
    const float* x     = (const float*)d_in[0];
    const float* wgt   = (const float*)d_in[1];
    const float* gamma = (const float*)d_in[2];
    const float* beta  = (const float*)d_in[3];
    float* out = (float*)d_out;

    double* stats = (double*)d_ws;                 // NSTAT*18 doubles = 4608 B
    float* P = (float*)((char*)d_ws + 8192);

    const size_t sig_bytes = (size_t)9 * NP * 4;   // 1.81 MB
    const size_t need4 = 8192 + (size_t)36 * NHW * 4 + sig_bytes;   // ~30.7 MB
    hipMemsetAsync(d_ws, 0, 8192, stream);

    if (ws_size >= need4) {
        float* sig_even = P + (size_t)36 * NHW;
        conv_split_kernel<4><<<1568, 256, 0, stream>>>(x, wgt, P);
        merge_stats_kernel<4><<<dim3(196, 9), 256, 0, stream>>>(P, stats, sig_even);
        apply_kernel<<<896, 256, 0, stream>>>(x, sig_even, gamma, beta, stats, out);
    } else {
        float* sig_even = P + (size_t)18 * NHW;
        conv_split_kernel<2><<<784, 256, 0, stream>>>(x, wgt, P);
        merge_stats_kernel<2><<<dim3(196, 9), 256, 0, stream>>>(P, stats, sig_even);
        apply_kernel<<<896, 256, 0, stream>>>(x, sig_even, gamma, beta, stats, out);
    }
}